// Round 1
// baseline (492.916 us; speedup 1.0000x reference)
//
#include <hip/hip_runtime.h>

// delta_layer: B=32, T=4096, D=256, window=2 (fp32).
// out[b,t] = concat(x[b,t], delta[b,t], double_delta[b,t])  -> 3*D floats.
// delta[t]  = (x[c(t+1)]-x[c(t-1)])/2 + (x[c(t+2)]-x[c(t-2)])/4, c = clamp to [0,T-1]
// ddelta[t] = (delta[c(t+1)]-delta[c(t-1)])/2 + (delta[c(t+2)]-delta[c(t-2)])/4
// NOTE double clamping: ddelta reads delta at r=c(t+j), and delta(r) reads x at c(r+i).

#define TT 4096
#define DD 256
#define D4 64   // float4 chunks per row
#define O4 192  // float4 chunks per output row (3*256/4)

__device__ __forceinline__ float4 dcomb(const float4 p1, const float4 m1,
                                        const float4 p2, const float4 m2) {
    float4 r;
    r.x = (p1.x - m1.x) * 0.5f + (p2.x - m2.x) * 0.25f;
    r.y = (p1.y - m1.y) * 0.5f + (p2.y - m2.y) * 0.25f;
    r.z = (p1.z - m1.z) * 0.5f + (p2.z - m2.z) * 0.25f;
    r.w = (p1.w - m1.w) * 0.5f + (p2.w - m2.w) * 0.25f;
    return r;
}

__device__ __forceinline__ int clampT(int s) {
    return s < 0 ? 0 : (s > TT - 1 ? TT - 1 : s);
}

__global__ __launch_bounds__(256) void delta_layer_kernel(
        const float* __restrict__ x, float* __restrict__ out, int nthreads) {
    int idx = blockIdx.x * 256 + threadIdx.x;
    if (idx >= nthreads) return;
    int d4 = idx & (D4 - 1);
    int bt = idx >> 6;           // b*T + t
    int t  = bt & (TT - 1);
    int b  = bt >> 12;

    // base pointer for this (b, d4): row r is at xrow[r * D4]
    const float4* xrow = reinterpret_cast<const float4*>(x)
                         + (long)b * TT * D4 + d4;

    float4 xt, Dm2, Dm1, D0, Dp1, Dp2;

    if (t >= 4 && t <= TT - 5) {
        // fast path: no clamping anywhere
        float4 xa[9];
        #pragma unroll
        for (int k = 0; k < 9; ++k) xa[k] = xrow[(long)(t - 4 + k) * D4];
        xt  = xa[4];
        Dm2 = dcomb(xa[3], xa[1], xa[4], xa[0]);
        Dm1 = dcomb(xa[4], xa[2], xa[5], xa[1]);
        D0  = dcomb(xa[5], xa[3], xa[6], xa[2]);
        Dp1 = dcomb(xa[6], xa[4], xa[7], xa[3]);
        Dp2 = dcomb(xa[7], xa[5], xa[8], xa[4]);
    } else {
        // boundary path: honor double-clamp semantics (loads hit L1/L2)
        auto X = [&](int s) -> float4 { return xrow[(long)clampT(s) * D4]; };
        auto Dat = [&](int r) -> float4 {   // r already clamped to [0,T-1]
            return dcomb(X(r + 1), X(r - 1), X(r + 2), X(r - 2));
        };
        xt  = X(t);
        D0  = Dat(t);
        Dm2 = Dat(clampT(t - 2));
        Dm1 = Dat(clampT(t - 1));
        Dp1 = Dat(clampT(t + 1));
        Dp2 = Dat(clampT(t + 2));
    }

    float4 dd = dcomb(Dp1, Dm1, Dp2, Dm2);

    float4* o = reinterpret_cast<float4*>(out) + (long)bt * O4 + d4;
    o[0]        = xt;
    o[D4]       = D0;
    o[2 * D4]   = dd;
}

extern "C" void kernel_launch(void* const* d_in, const int* in_sizes, int n_in,
                              void* d_out, int out_size, void* d_ws, size_t ws_size,
                              hipStream_t stream) {
    const float* x = (const float*)d_in[0];
    float* out = (float*)d_out;
    int n_elem = in_sizes[0];            // B*T*D
    int nthreads = n_elem / 4;           // one thread per float4 chunk
    int blocks = (nthreads + 255) / 256;
    delta_layer_kernel<<<blocks, 256, 0, stream>>>(x, out, nthreads);
}

// Round 2
// 491.710 us; speedup vs baseline: 1.0025x; 1.0025x over previous
//
#include <hip/hip_runtime.h>

// delta_layer: B=32, T=4096, D=256, window=2 (fp32).
// out[b,t] = concat(x[b,t], delta[b,t], double_delta[b,t])  -> 3*D floats.
// delta[t]  = (x[c(t+1)]-x[c(t-1)])/2 + (x[c(t+2)]-x[c(t-2)])/4, c = clamp to [0,T-1]
// ddelta[t] = (delta[c(t+1)]-delta[c(t-1)])/2 + (delta[c(t+2)]-delta[c(t-2)])/4
// Double-clamp semantics: ddelta reads delta at r=c(t+j); delta(r) reads x[c(r+i)].
//
// Streaming design: thread owns (b, d4-chunk, 32 consecutive t). Registers hold
// x[c(t)..c(t+4)] ring + delta[c(t-2)..c(t+2)] ring. Per t: 1 load, 1 new delta,
// 3 stores. Load amplification 1.28x (rows) vs 9x in the naive per-t kernel.

#define TT   4096
#define D4   64    // float4 chunks per row
#define O4   192   // float4 chunks per output row (3*256/4)
#define TRUN 32    // t's per thread

__device__ __forceinline__ float4 dcomb(const float4 p1, const float4 m1,
                                        const float4 p2, const float4 m2) {
    float4 r;
    r.x = (p1.x - m1.x) * 0.5f + (p2.x - m2.x) * 0.25f;
    r.y = (p1.y - m1.y) * 0.5f + (p2.y - m2.y) * 0.25f;
    r.z = (p1.z - m1.z) * 0.5f + (p2.z - m2.z) * 0.25f;
    r.w = (p1.w - m1.w) * 0.5f + (p2.w - m2.w) * 0.25f;
    return r;
}

__device__ __forceinline__ int clampT(int s) {
    return s < 0 ? 0 : (s > TT - 1 ? TT - 1 : s);
}

__global__ __launch_bounds__(256) void delta_layer_kernel(
        const float* __restrict__ x, float* __restrict__ out) {
    int idx = blockIdx.x * 256 + threadIdx.x;
    int d4  = idx & (D4 - 1);
    int seg = idx >> 6;               // lane-uniform: (b, t-block)
    int t0  = (seg & (TT / TRUN - 1)) * TRUN;
    int b   = seg >> 7;               // T/TRUN = 128

    const float4* xb = reinterpret_cast<const float4*>(x) + b * TT * D4 + d4;

    auto ldc = [&](int r) -> float4 { return xb[clampT(r) * D4]; };
    // delta at a VALID row r (r in [0,T-1]), with x-index clamping:
    auto deltaAt = [&](int r) -> float4 {
        return dcomb(ldc(r + 1), ldc(r - 1), ldc(r + 2), ldc(r - 2));
    };

    // Prime delta ring: delta[c(t0-2)] .. delta[c(t0+2)]  (double-clamp correct)
    float4 dm2 = deltaAt(clampT(t0 - 2));
    float4 dm1 = deltaAt(clampT(t0 - 1));
    float4 dc  = deltaAt(t0);
    float4 dp1 = deltaAt(clampT(t0 + 1));
    float4 dp2 = deltaAt(clampT(t0 + 2));
    // Prime x ring: x[c(t0)] .. x[c(t0+4)]
    float4 x0 = ldc(t0),     x1 = ldc(t0 + 1), x2 = ldc(t0 + 2);
    float4 x3 = ldc(t0 + 3), x4 = ldc(t0 + 4);

    float4* ob = reinterpret_cast<float4*>(out) + (b * TT + t0) * O4 + d4;

    #pragma unroll
    for (int tt = 0; tt < TRUN; ++tt) {
        int t = t0 + tt;
        ob[0]      = x0;                          // x[t]
        ob[D4]     = dc;                          // delta[t]
        ob[2 * D4] = dcomb(dp1, dm1, dp2, dm2);   // ddelta[t]

        // advance to t+1: need x[c(t+5)] and delta[c(t+3)]
        float4 xn = ldc(t + 5);
        float4 dn;
        if (t + 3 <= TT - 1) {
            // delta[t+3] = (x[c(t+4)]-x[c(t+2)])/2 + (x[c(t+5)]-x[c(t+1)])/4
            dn = dcomb(x4, x2, xn, x1);
        } else {
            dn = dp2;                             // delta index clamps to T-1
        }
        dm2 = dm1; dm1 = dc; dc = dp1; dp1 = dp2; dp2 = dn;
        x0 = x1; x1 = x2; x2 = x3; x3 = x4; x4 = xn;
        ob += O4;
    }
}

extern "C" void kernel_launch(void* const* d_in, const int* in_sizes, int n_in,
                              void* d_out, int out_size, void* d_ws, size_t ws_size,
                              hipStream_t stream) {
    const float* x = (const float*)d_in[0];
    float* out = (float*)d_out;
    // threads = B * (T/TRUN) * D4 = 32 * 128 * 64 = 262144
    int nthreads = (in_sizes[0] / 256 / TRUN) * D4;  // robust to B changes
    int blocks = (nthreads + 255) / 256;
    delta_layer_kernel<<<blocks, 256, 0, stream>>>(x, out);
}